// Round 1
// baseline (89.063 us; speedup 1.0000x reference)
//
#include <hip/hip_runtime.h>

#define EPS 1e-10f

// Fused dual-loss reduction:
//   wmse partial: sum over (weight[row] * (target - input))^2
//   wcl  partial: sum over |(st*log(tp+eps) + (1-st)*log(1-tp+eps)) * so|
__global__ __launch_bounds__(256) void loss_reduce_kernel(
    const float* __restrict__ input,
    const float* __restrict__ target,
    const float* __restrict__ weight,
    const float* __restrict__ sub_target,
    const float* __restrict__ target_pre,
    const float* __restrict__ sub_obrT,
    double* __restrict__ acc,   // acc[0]=wmse sum, acc[1]=wcl sum
    int n4,                      // total float4 count = N*D/4
    int d4)                      // D/4 (elements per row in float4 units)
{
    const float4* __restrict__ in4 = (const float4*)input;
    const float4* __restrict__ tg4 = (const float4*)target;
    const float4* __restrict__ st4 = (const float4*)sub_target;
    const float4* __restrict__ tp4 = (const float4*)target_pre;
    const float4* __restrict__ so4 = (const float4*)sub_obrT;

    float s_mse = 0.0f;
    float s_wcl = 0.0f;

    int idx = blockIdx.x * blockDim.x + threadIdx.x;
    int stride = gridDim.x * blockDim.x;

    for (int i = idx; i < n4; i += stride) {
        float w  = weight[i / d4];
        float w2 = w * w;
        float4 x  = in4[i];
        float4 t  = tg4[i];
        float4 st = st4[i];
        float4 tp = tp4[i];
        float4 so = so4[i];

        // wmse terms
        float d0 = t.x - x.x, d1 = t.y - x.y, d2 = t.z - x.z, d3 = t.w - x.w;
        s_mse += w2 * (d0 * d0);
        s_mse += w2 * (d1 * d1);
        s_mse += w2 * (d2 * d2);
        s_mse += w2 * (d3 * d3);

        // weighted CL terms (fast log: v_log_f32-based, ~1e-7 rel err, fine
        // for the 1.3e-2 abs threshold)
        float b0 = st.x * __logf(tp.x + EPS) + (1.0f - st.x) * __logf(1.0f - tp.x + EPS);
        float b1 = st.y * __logf(tp.y + EPS) + (1.0f - st.y) * __logf(1.0f - tp.y + EPS);
        float b2 = st.z * __logf(tp.z + EPS) + (1.0f - st.z) * __logf(1.0f - tp.z + EPS);
        float b3 = st.w * __logf(tp.w + EPS) + (1.0f - st.w) * __logf(1.0f - tp.w + EPS);
        s_wcl += fabsf(b0 * so.x);
        s_wcl += fabsf(b1 * so.y);
        s_wcl += fabsf(b2 * so.z);
        s_wcl += fabsf(b3 * so.w);
    }

    // wave (64-lane) shuffle reduction
    for (int off = 32; off > 0; off >>= 1) {
        s_mse += __shfl_down(s_mse, off, 64);
        s_wcl += __shfl_down(s_wcl, off, 64);
    }

    // block reduction across 4 waves via LDS
    __shared__ float lds_mse[4];
    __shared__ float lds_wcl[4];
    int lane = threadIdx.x & 63;
    int wid  = threadIdx.x >> 6;
    if (lane == 0) {
        lds_mse[wid] = s_mse;
        lds_wcl[wid] = s_wcl;
    }
    __syncthreads();
    if (threadIdx.x == 0) {
        float bm = lds_mse[0] + lds_mse[1] + lds_mse[2] + lds_mse[3];
        float bc = lds_wcl[0] + lds_wcl[1] + lds_wcl[2] + lds_wcl[3];
        atomicAdd(&acc[0], (double)bm);
        atomicAdd(&acc[1], (double)bc);
    }
}

// Scalar-tail kernel (handles N*D not divisible by 4; no-op for this shape)
__global__ void loss_tail_kernel(
    const float* __restrict__ input,
    const float* __restrict__ target,
    const float* __restrict__ weight,
    const float* __restrict__ sub_target,
    const float* __restrict__ target_pre,
    const float* __restrict__ sub_obrT,
    double* __restrict__ acc,
    int start, int total, int D)
{
    if (blockIdx.x == 0 && threadIdx.x == 0) {
        double sm = 0.0, sc = 0.0;
        for (int i = start; i < total; ++i) {
            float w = weight[i / D];
            float d = target[i] - input[i];
            sm += (double)(w * w * d * d);
            float st = sub_target[i], tp = target_pre[i];
            float b = st * __logf(tp + EPS) + (1.0f - st) * __logf(1.0f - tp + EPS);
            sc += (double)fabsf(b * sub_obrT[i]);
        }
        if (sm != 0.0) atomicAdd(&acc[0], sm);
        if (sc != 0.0) atomicAdd(&acc[1], sc);
    }
}

__global__ void loss_finalize_kernel(const double* __restrict__ acc,
                                     float* __restrict__ out,
                                     double inv_count)
{
    if (threadIdx.x == 0 && blockIdx.x == 0) {
        out[0] = (float)(acc[0] * inv_count);
        out[1] = (float)(acc[1] * inv_count);
    }
}

extern "C" void kernel_launch(void* const* d_in, const int* in_sizes, int n_in,
                              void* d_out, int out_size, void* d_ws, size_t ws_size,
                              hipStream_t stream) {
    const float* input      = (const float*)d_in[0];
    const float* target     = (const float*)d_in[1];
    const float* weight     = (const float*)d_in[2];
    const float* sub_target = (const float*)d_in[3];
    const float* target_pre = (const float*)d_in[4];
    const float* sub_obrT   = (const float*)d_in[5];
    float* out = (float*)d_out;

    const int ND = in_sizes[0];      // N*D
    const int N  = in_sizes[2];      // weight length
    const int D  = ND / N;
    const int n4 = ND / 4;
    const int d4 = D / 4;

    double* acc = (double*)d_ws;

    // zero the two accumulators (graph-capture-safe async memset)
    hipMemsetAsync(acc, 0, 2 * sizeof(double), stream);

    int block = 256;
    int grid = (n4 + block - 1) / block;
    if (grid > 2048) grid = 2048;
    if (grid < 1) grid = 1;

    loss_reduce_kernel<<<grid, block, 0, stream>>>(
        input, target, weight, sub_target, target_pre, sub_obrT, acc, n4, d4);

    if (n4 * 4 < ND) {
        loss_tail_kernel<<<1, 1, 0, stream>>>(
            input, target, weight, sub_target, target_pre, sub_obrT, acc,
            n4 * 4, ND, D);
    }

    loss_finalize_kernel<<<1, 1, 0, stream>>>(acc, out, 1.0 / (double)ND);
}